// Round 2
// baseline (146.096 us; speedup 1.0000x reference)
//
#include <hip/hip_runtime.h>
#include <hip/hip_bf16.h>
#include <math.h>

// Problem constants
#define BATCH 8
#define HH 512
#define WW 512
#define COUT 256
#define NPTS 11          // 5 + 6
#define CASC 3
#define FH 128           // conv output spatial
#define FW 128
#define KT 49            // 7x7 taps
#define NBK (BATCH*NPTS) // 88
#define NSPLIT 128       // argmax row-splits per image (fused: one block each)
#define OROWS (HH/NSPLIT) // 4 output rows per split
#define MAXR 3           // max feature rows a split touches (span<=1 +1 +1)

// ws layout (floats)
// fold: [0..538]   scoreW in [t][k] layout (t*11+k)
//       [539..549] scoreB[k]
//       [550..843] shiftW[i*2+j][t] (49 each)
//       [844..849] shiftB
#define FOLD_OFF   0
#define PVAL_OFF   1024                      // 88*128 = 11264 floats
#define PIDX_OFF   (PVAL_OFF + NBK*NSPLIT)   // 11264 ints

#define STEPC (127.0f/511.0f)

// ---------------------------------------------------------------------------
// Kernel 1: fold weights. One wave per output (850 outputs = 17 rows x 50
// cols; col 49 = bias). 213 blocks x 256 threads (4 waves/block).
// NOTE (R3 post-mortem): do NOT fuse the downstream cascade via last-block
// atomics — 704 device-scope atomicAdd + __threadfence cost ~45 us on
// multi-XCD gfx950. Separate kernels are faster.
// NOTE (R5): fold stays a SEPARATE kernel — its lane-strided sum + shfl
// reduction order is what the absmax=0.0 record was verified against.
__global__ __launch_bounds__(256) void fold_kernel(
    const float* __restrict__ bw, const float* __restrict__ bb,
    const float* __restrict__ fcw, const float* __restrict__ fcb,
    const float* __restrict__ hw, const float* __restrict__ hb,
    float* __restrict__ fold) {
  int id = blockIdx.x*4 + (threadIdx.x >> 6);   // 0..851
  if (id >= 850) return;
  int row = id / 50, t = id % 50;
  int lane = threadIdx.x & 63;
  float acc = 0.f;
  for (int c = lane; c < COUT; c += 64) {
    float coef;
    if (row < NPTS) {
      coef = fcw[row*COUT + c];
    } else {
      int r = row - NPTS;
      coef = hw[(r >> 1)*(COUT*2) + c*2 + (r & 1)];
    }
    float wsum;
    if (t < KT) {
      const float* p = bw + c*(3*KT) + t;
      wsum = p[0] + p[KT] + p[2*KT];
    } else {
      wsum = bb[c];
    }
    acc += coef * wsum;
  }
  #pragma unroll
  for (int off = 32; off > 0; off >>= 1) acc += __shfl_down(acc, off);
  if (lane == 0) {
    if (t == KT) acc += (row < NPTS) ? fcb[row] : hb[row - NPTS];
    if (row < NPTS) {
      if (t < KT) fold[t*NPTS + row] = acc;                   // [t][k] layout
      else        fold[NPTS*KT + row] = acc;                  // scoreB at 539..549
    } else {
      int r = row - NPTS;
      if (t < KT) fold[550 + r*KT + t] = acc;                 // shiftW
      else        fold[844 + r] = acc;                        // shiftB
    }
  }
}

// ---------------------------------------------------------------------------
// Kernel 2 (fused, R6): per-split conv + candidate argmax.
// R5 post-mortem: 256 blocks = 1 wave/SIMD -> latency-bound, 41 us.
// R6 fix: OROWS=4 -> MAXR=3 feature rows, LDS 17 KB, grid 1024 blocks
// (4 blocks/CU, 4 waves/SIMD). Conv recompute 3x unique rows = 212M FMA
// chip-wide (~2.7 us VALU) — cheap. blockIdx swizzle b=blk&7 puts each
// image's 128 splits on ONE XCD (round-robin dispatch) so the 1 MB image
// is L2-resident there and the 3x re-reads never reach HBM.
// Conv per-pixel arithmetic and candidate scan are VERBATIM from the
// absmax=0.0 kernels. Splits with no candidate rows emit -FLT_MAX
// sentinels; the (val desc, idx asc) merge is a total order so this is
// harmless.
__global__ __launch_bounds__(256) void score_argmax_kernel(
    const float* __restrict__ img, const float* __restrict__ fold,
    float* __restrict__ pval, int* __restrict__ pidx) {
  __shared__ __align__(16) float s[NPTS*MAXR*FW];   // 11*3*128*4 = 16896 B
  __shared__ float wvv[NPTS*4];
  __shared__ int   wvi[NPTS*4];
  int b = blockIdx.x & 7;     // image -> XCD (dispatch round-robins % 8)
  int q = blockIdx.x >> 3;    // split 0..127

  int oyb = q*OROWS;
  int ybase = (int)((float)oyb * STEPC);
  int ylast = (int)((float)(oyb + OROWS - 1) * STEPC);
  int yend  = min(ylast + 1, FH - 1);
  int rows  = yend - ybase + 1;              // <= 3
  const float* im = img + (size_t)b * (HH*WW);

  // --- conv phase: rows x 128 pixels, 11 channels each, into LDS ---
  for (int p = threadIdx.x; p < rows*FW; p += 256) {
    int ry = p >> 7;                 // 0..rows-1
    int x  = p & 127;
    int y  = ybase + ry;
    float acc[NPTS];
    #pragma unroll
    for (int k = 0; k < NPTS; ++k) acc[k] = fold[NPTS*KT + k];   // uniform -> s_load
    int iy0 = y*4 - 3, ix0 = x*4 - 3;
    #pragma unroll
    for (int kh = 0; kh < 7; ++kh) {
      int iy = iy0 + kh;
      if (iy < 0 || iy >= HH) continue;
      #pragma unroll
      for (int kw = 0; kw < 7; ++kw) {
        int ix = ix0 + kw;
        if (ix < 0 || ix >= WW) continue;
        float xv = im[iy*WW + ix] - 0.5f;
        int t = kh*7 + kw;
        #pragma unroll
        for (int k = 0; k < NPTS; ++k) acc[k] = fmaf(fold[t*NPTS + k], xv, acc[k]);
      }
    }
    #pragma unroll
    for (int k = 0; k < NPTS; ++k) s[(k*MAXR + ry)*FW + x] = acc[k];
  }
  __syncthreads();

  // --- argmax phase: verbatim candidate logic ---
  // per-thread candidate column: thread t owns x-bucket t>>1, (t&1 ? last :
  // first) sampled col of that bucket. kb=127 is the singleton {511} (dup ok).
  int t = threadIdx.x;
  int kb = t >> 1;
  int cf = (kb*511 + 126)/127;
  int cl = (kb < 127) ? ((kb + 1)*511 + 126)/127 - 1 : 511;
  int ox = (t & 1) ? cl : cf;
  float tx = (float)ox * STEPC;
  int xa0 = (int)tx;
  float wx = tx - (float)xa0;
  int xa1 = min(xa0 + 1, FW - 1);
  float omwx = 1.f - wx;
  int wave = threadIdx.x >> 6;
  int lane = threadIdx.x & 63;

  #pragma unroll
  for (int ch = 0; ch < NPTS; ++ch) {
    float best = -3.4028235e38f;
    int bidx = 0x7fffffff;
    for (int k = ybase; k <= ylast; ++k) {   // y-buckets intersecting split
      int y1 = min(k + 1, FH - 1);
      const float* r0 = s + (ch*MAXR + (k  - ybase))*FW;
      const float* r1 = s + (ch*MAXR + (y1 - ybase))*FW;
      float A = r0[xa0], B = r1[xa0], C = r0[xa1], D = r1[xa1];
      int rf = (k*511 + 126)/127;                              // first row of bucket
      int rl = (k < 127) ? ((k + 1)*511 + 126)/127 - 1 : 511;  // last row
      if (rf >= oyb && rf < oyb + OROWS) {
        float ty = (float)rf * STEPC;
        int y0i = (int)ty;
        float wy = ty - (float)y0i;
        float omwy = 1.f - wy;
        float top0 = A*omwy + B*wy;
        float top1 = C*omwy + D*wy;
        float v = top0*omwx + top1*wx;
        if (v > best) { best = v; bidx = rf*512 + ox; }
      }
      if (rl != rf && rl >= oyb && rl < oyb + OROWS) {
        float ty = (float)rl * STEPC;
        int y0i = (int)ty;
        float wy = ty - (float)y0i;
        float omwy = 1.f - wy;
        float top0 = A*omwy + B*wy;
        float top1 = C*omwy + D*wy;
        float v = top0*omwx + top1*wx;
        if (v > best) { best = v; bidx = rl*512 + ox; }
      }
    }
    // intra-wave reduce (value desc, index asc tie-break) — no barriers
    #pragma unroll
    for (int off = 32; off > 0; off >>= 1) {
      float ov = __shfl_down(best, off);
      int   oi = __shfl_down(bidx, off);
      if (ov > best || (ov == best && oi < bidx)) { best = ov; bidx = oi; }
    }
    if (lane == 0) { wvv[ch*4 + wave] = best; wvi[ch*4 + wave] = bidx; }
  }
  __syncthreads();
  if (threadIdx.x < NPTS) {
    int ch = threadIdx.x;
    float best = wvv[ch*4]; int bidx = wvi[ch*4];
    #pragma unroll
    for (int w = 1; w < 4; ++w) {
      float ov = wvv[ch*4 + w]; int oi = wvi[ch*4 + w];
      if (ov > best || (ov == best && oi < bidx)) { best = ov; bidx = oi; }
    }
    int bk = b*NPTS + ch;
    pval[bk*NSPLIT + q] = best;
    pidx[bk*NSPLIT + q] = bidx;
  }
}

// ---------------------------------------------------------------------------
// Kernel 3: merge partials -> coords, then 3 cascade refinements with folded
// shift weights (direct conv at the gathered point), write final coords.
// Merge is a total order over (val desc, idx asc) -> q scan order free.
__global__ __launch_bounds__(128) void cascade_kernel(
    const float* __restrict__ img, const float* __restrict__ fold,
    const float* __restrict__ pval, const int* __restrict__ pidx,
    float* __restrict__ out) {
  int p = threadIdx.x;    // bk index = b*11 + k
  if (p >= NBK) return;
  float best = pval[p*NSPLIT]; int bidx = pidx[p*NSPLIT];
  #pragma unroll 16
  for (int q = 1; q < NSPLIT; ++q) {
    float v = pval[p*NSPLIT + q]; int i = pidx[p*NSPLIT + q];
    if (v > best || (v == best && i < bidx)) { best = v; bidx = i; }
  }
  float cx = (float)(bidx & 511);
  float cy = (float)(bidx >> 9);
  int b = p / NPTS;
  const float* im = img + (size_t)b * (HH*WW);
  for (int i = 0; i < CASC; ++i) {
    // hi from y-coord, wi from x-coord; jnp.round = RNE = rintf
    float ry = rintf(cy * 0.25f), rx = rintf(cx * 0.25f);
    int hi = (int)fminf(fmaxf(ry, 0.f), (float)(FH - 1));
    int wi = (int)fminf(fmaxf(rx, 0.f), (float)(FW - 1));
    float s0 = fold[844 + i*2 + 0];
    float s1 = fold[844 + i*2 + 1];
    int iy0 = hi*4 - 3, ix0 = wi*4 - 3;
    for (int kh = 0; kh < 7; ++kh) {
      int iy = iy0 + kh;
      if (iy < 0 || iy >= HH) continue;
      for (int kw = 0; kw < 7; ++kw) {
        int ix = ix0 + kw;
        if (ix < 0 || ix >= WW) continue;
        float xv = im[iy*WW + ix] - 0.5f;
        int t = kh*7 + kw;
        s0 = fmaf(fold[550 + (i*2 + 0)*KT + t], xv, s0);
        s1 = fmaf(fold[550 + (i*2 + 1)*KT + t], xv, s1);
      }
    }
    cx += s0;
    cy += s1;
  }
  out[p*2 + 0] = cx;
  out[p*2 + 1] = cy;
}

// ---------------------------------------------------------------------------
extern "C" void kernel_launch(void* const* d_in, const int* in_sizes, int n_in,
                              void* d_out, int out_size, void* d_ws, size_t ws_size,
                              hipStream_t stream) {
  const float* img = (const float*)d_in[0];   // (8,1,512,512)
  const float* bw  = (const float*)d_in[1];   // (256,3,7,7)
  const float* bb  = (const float*)d_in[2];   // (256,)
  const float* fcw = (const float*)d_in[3];   // (11,256)
  const float* fcb = (const float*)d_in[4];   // (11,)
  const float* hw  = (const float*)d_in[5];   // (3,256,2)
  const float* hb  = (const float*)d_in[6];   // (3,2)
  float* out = (float*)d_out;                 // (8,11,2) f32

  float* ws     = (float*)d_ws;
  float* fold   = ws + FOLD_OFF;
  float* pval   = ws + PVAL_OFF;
  int*   pidx   = (int*)(ws + PIDX_OFF);

  fold_kernel<<<213, 256, 0, stream>>>(bw, bb, fcw, fcb, hw, hb, fold);
  score_argmax_kernel<<<BATCH*NSPLIT, 256, 0, stream>>>(img, fold, pval, pidx);
  cascade_kernel<<<1, 128, 0, stream>>>(img, fold, pval, pidx, out);
}

// Round 3
// 118.810 us; speedup vs baseline: 1.2297x; 1.2297x over previous
//
#include <hip/hip_runtime.h>
#include <hip/hip_bf16.h>
#include <math.h>

// Problem constants
#define BATCH 8
#define HH 512
#define WW 512
#define COUT 256
#define NPTS 11          // 5 + 6
#define CASC 3
#define FH 128           // conv output spatial
#define FW 128
#define KT 49            // 7x7 taps
#define NBK (BATCH*NPTS) // 88
#define NSPLIT 128       // argmax row-splits per image (fused: one block each)
#define OROWS (HH/NSPLIT) // 4 output rows per split
#define MAXR 3           // max feature rows a split touches (span<=1 +1 +1)

// ws layout (floats)
// fold: [0..538]   scoreW in [t][k] layout (t*11+k)
//       [539..549] scoreB[k]
//       [550..843] shiftW[i*2+j][t] (49 each)
//       [844..849] shiftB
#define FOLD_OFF   0
#define PVAL_OFF   1024                      // 88*128 = 11264 floats
#define PIDX_OFF   (PVAL_OFF + NBK*NSPLIT)   // 11264 ints

#define STEPC (127.0f/511.0f)

// ---------------------------------------------------------------------------
// Kernel 1: fold weights. One wave per output (850 outputs = 17 rows x 50
// cols; col 49 = bias). 213 blocks x 256 threads (4 waves/block).
// NOTE (R3 post-mortem): do NOT fuse the downstream cascade via last-block
// atomics — 704 device-scope atomicAdd + __threadfence cost ~45 us on
// multi-XCD gfx950. Separate kernels are faster.
// NOTE (R5): fold stays a SEPARATE kernel — its lane-strided sum + shfl
// reduction order is what the absmax=0.0 record was verified against.
__global__ __launch_bounds__(256) void fold_kernel(
    const float* __restrict__ bw, const float* __restrict__ bb,
    const float* __restrict__ fcw, const float* __restrict__ fcb,
    const float* __restrict__ hw, const float* __restrict__ hb,
    float* __restrict__ fold) {
  int id = blockIdx.x*4 + (threadIdx.x >> 6);   // 0..851
  if (id >= 850) return;
  int row = id / 50, t = id % 50;
  int lane = threadIdx.x & 63;
  float acc = 0.f;
  for (int c = lane; c < COUT; c += 64) {
    float coef;
    if (row < NPTS) {
      coef = fcw[row*COUT + c];
    } else {
      int r = row - NPTS;
      coef = hw[(r >> 1)*(COUT*2) + c*2 + (r & 1)];
    }
    float wsum;
    if (t < KT) {
      const float* p = bw + c*(3*KT) + t;
      wsum = p[0] + p[KT] + p[2*KT];
    } else {
      wsum = bb[c];
    }
    acc += coef * wsum;
  }
  #pragma unroll
  for (int off = 32; off > 0; off >>= 1) acc += __shfl_down(acc, off);
  if (lane == 0) {
    if (t == KT) acc += (row < NPTS) ? fcb[row] : hb[row - NPTS];
    if (row < NPTS) {
      if (t < KT) fold[t*NPTS + row] = acc;                   // [t][k] layout
      else        fold[NPTS*KT + row] = acc;                  // scoreB at 539..549
    } else {
      int r = row - NPTS;
      if (t < KT) fold[550 + r*KT + t] = acc;                 // shiftW
      else        fold[844 + r] = acc;                        // shiftB
    }
  }
}

// ---------------------------------------------------------------------------
// Kernel 2 (fused, R6): per-split conv + candidate argmax.
// R5 post-mortem: 256 blocks = 1 wave/SIMD -> latency-bound, 41 us.
// R6 fix: OROWS=4 -> MAXR=3 feature rows, LDS 17 KB, grid 1024 blocks
// (4 blocks/CU, 4 waves/SIMD). blockIdx swizzle b=blk&7 puts each image's
// 128 splits on ONE XCD (round-robin dispatch) so the image stays
// L2-resident and the 3x row re-reads never reach HBM.
// Conv per-pixel arithmetic and candidate scan are VERBATIM from the
// absmax=0.0 kernels. Splits with no candidate rows emit -FLT_MAX
// sentinels; the (val desc, idx asc) merge is a total order so this is
// harmless.
__global__ __launch_bounds__(256) void score_argmax_kernel(
    const float* __restrict__ img, const float* __restrict__ fold,
    float* __restrict__ pval, int* __restrict__ pidx) {
  __shared__ __align__(16) float s[NPTS*MAXR*FW];   // 11*3*128*4 = 16896 B
  __shared__ float wvv[NPTS*4];
  __shared__ int   wvi[NPTS*4];
  int b = blockIdx.x & 7;     // image -> XCD (dispatch round-robins % 8)
  int q = blockIdx.x >> 3;    // split 0..127

  int oyb = q*OROWS;
  int ybase = (int)((float)oyb * STEPC);
  int ylast = (int)((float)(oyb + OROWS - 1) * STEPC);
  int yend  = min(ylast + 1, FH - 1);
  int rows  = yend - ybase + 1;              // <= 3
  const float* im = img + (size_t)b * (HH*WW);

  // --- conv phase: rows x 128 pixels, 11 channels each, into LDS ---
  for (int p = threadIdx.x; p < rows*FW; p += 256) {
    int ry = p >> 7;                 // 0..rows-1
    int x  = p & 127;
    int y  = ybase + ry;
    float acc[NPTS];
    #pragma unroll
    for (int k = 0; k < NPTS; ++k) acc[k] = fold[NPTS*KT + k];   // uniform -> s_load
    int iy0 = y*4 - 3, ix0 = x*4 - 3;
    #pragma unroll
    for (int kh = 0; kh < 7; ++kh) {
      int iy = iy0 + kh;
      if (iy < 0 || iy >= HH) continue;
      #pragma unroll
      for (int kw = 0; kw < 7; ++kw) {
        int ix = ix0 + kw;
        if (ix < 0 || ix >= WW) continue;
        float xv = im[iy*WW + ix] - 0.5f;
        int t = kh*7 + kw;
        #pragma unroll
        for (int k = 0; k < NPTS; ++k) acc[k] = fmaf(fold[t*NPTS + k], xv, acc[k]);
      }
    }
    #pragma unroll
    for (int k = 0; k < NPTS; ++k) s[(k*MAXR + ry)*FW + x] = acc[k];
  }
  __syncthreads();

  // --- argmax phase: verbatim candidate logic ---
  // per-thread candidate column: thread t owns x-bucket t>>1, (t&1 ? last :
  // first) sampled col of that bucket. kb=127 is the singleton {511} (dup ok).
  int t = threadIdx.x;
  int kb = t >> 1;
  int cf = (kb*511 + 126)/127;
  int cl = (kb < 127) ? ((kb + 1)*511 + 126)/127 - 1 : 511;
  int ox = (t & 1) ? cl : cf;
  float tx = (float)ox * STEPC;
  int xa0 = (int)tx;
  float wx = tx - (float)xa0;
  int xa1 = min(xa0 + 1, FW - 1);
  float omwx = 1.f - wx;
  int wave = threadIdx.x >> 6;
  int lane = threadIdx.x & 63;

  #pragma unroll
  for (int ch = 0; ch < NPTS; ++ch) {
    float best = -3.4028235e38f;
    int bidx = 0x7fffffff;
    for (int k = ybase; k <= ylast; ++k) {   // y-buckets intersecting split
      int y1 = min(k + 1, FH - 1);
      const float* r0 = s + (ch*MAXR + (k  - ybase))*FW;
      const float* r1 = s + (ch*MAXR + (y1 - ybase))*FW;
      float A = r0[xa0], B = r1[xa0], C = r0[xa1], D = r1[xa1];
      int rf = (k*511 + 126)/127;                              // first row of bucket
      int rl = (k < 127) ? ((k + 1)*511 + 126)/127 - 1 : 511;  // last row
      if (rf >= oyb && rf < oyb + OROWS) {
        float ty = (float)rf * STEPC;
        int y0i = (int)ty;
        float wy = ty - (float)y0i;
        float omwy = 1.f - wy;
        float top0 = A*omwy + B*wy;
        float top1 = C*omwy + D*wy;
        float v = top0*omwx + top1*wx;
        if (v > best) { best = v; bidx = rf*512 + ox; }
      }
      if (rl != rf && rl >= oyb && rl < oyb + OROWS) {
        float ty = (float)rl * STEPC;
        int y0i = (int)ty;
        float wy = ty - (float)y0i;
        float omwy = 1.f - wy;
        float top0 = A*omwy + B*wy;
        float top1 = C*omwy + D*wy;
        float v = top0*omwx + top1*wx;
        if (v > best) { best = v; bidx = rl*512 + ox; }
      }
    }
    // intra-wave reduce (value desc, index asc tie-break) — no barriers
    #pragma unroll
    for (int off = 32; off > 0; off >>= 1) {
      float ov = __shfl_down(best, off);
      int   oi = __shfl_down(bidx, off);
      if (ov > best || (ov == best && oi < bidx)) { best = ov; bidx = oi; }
    }
    if (lane == 0) { wvv[ch*4 + wave] = best; wvi[ch*4 + wave] = bidx; }
  }
  __syncthreads();
  if (threadIdx.x < NPTS) {
    int ch = threadIdx.x;
    float best = wvv[ch*4]; int bidx = wvi[ch*4];
    #pragma unroll
    for (int w = 1; w < 4; ++w) {
      float ov = wvv[ch*4 + w]; int oi = wvi[ch*4 + w];
      if (ov > best || (ov == best && oi < bidx)) { best = ov; bidx = oi; }
    }
    int bk = b*NPTS + ch;
    pval[bk*NSPLIT + q] = best;
    pidx[bk*NSPLIT + q] = bidx;
  }
}

// ---------------------------------------------------------------------------
// Kernel 3 (R7): one block per (b,k) point. R6 post-mortem: single-block
// serial merge of 128 partials = 46 us of exposed cross-XCD load latency.
// The (val desc, idx asc) comparator is an associative/commutative
// semilattice max -> parallel wave-reduce gives the BIT-IDENTICAL winner.
// 88 blocks x 64 lanes: lane q merges partials {q, q+64}, shuffle-reduce,
// then lane 0 runs the 3-cascade refinement VERBATIM (absmax=0.0 path).
__global__ __launch_bounds__(64) void cascade_kernel(
    const float* __restrict__ img, const float* __restrict__ fold,
    const float* __restrict__ pval, const int* __restrict__ pidx,
    float* __restrict__ out) {
  int p = blockIdx.x;          // bk index = b*11 + k
  int lane = threadIdx.x;      // 0..63
  float best = pval[p*NSPLIT + lane];
  int   bidx = pidx[p*NSPLIT + lane];
  {
    float v1 = pval[p*NSPLIT + 64 + lane];
    int   i1 = pidx[p*NSPLIT + 64 + lane];
    if (v1 > best || (v1 == best && i1 < bidx)) { best = v1; bidx = i1; }
  }
  #pragma unroll
  for (int off = 32; off > 0; off >>= 1) {
    float ov = __shfl_down(best, off);
    int   oi = __shfl_down(bidx, off);
    if (ov > best || (ov == best && oi < bidx)) { best = ov; bidx = oi; }
  }
  if (lane != 0) return;

  float cx = (float)(bidx & 511);
  float cy = (float)(bidx >> 9);
  int b = p / NPTS;
  const float* im = img + (size_t)b * (HH*WW);
  for (int i = 0; i < CASC; ++i) {
    // hi from y-coord, wi from x-coord; jnp.round = RNE = rintf
    float ry = rintf(cy * 0.25f), rx = rintf(cx * 0.25f);
    int hi = (int)fminf(fmaxf(ry, 0.f), (float)(FH - 1));
    int wi = (int)fminf(fmaxf(rx, 0.f), (float)(FW - 1));
    float s0 = fold[844 + i*2 + 0];
    float s1 = fold[844 + i*2 + 1];
    int iy0 = hi*4 - 3, ix0 = wi*4 - 3;
    for (int kh = 0; kh < 7; ++kh) {
      int iy = iy0 + kh;
      if (iy < 0 || iy >= HH) continue;
      for (int kw = 0; kw < 7; ++kw) {
        int ix = ix0 + kw;
        if (ix < 0 || ix >= WW) continue;
        float xv = im[iy*WW + ix] - 0.5f;
        int t = kh*7 + kw;
        s0 = fmaf(fold[550 + (i*2 + 0)*KT + t], xv, s0);
        s1 = fmaf(fold[550 + (i*2 + 1)*KT + t], xv, s1);
      }
    }
    cx += s0;
    cy += s1;
  }
  out[p*2 + 0] = cx;
  out[p*2 + 1] = cy;
}

// ---------------------------------------------------------------------------
extern "C" void kernel_launch(void* const* d_in, const int* in_sizes, int n_in,
                              void* d_out, int out_size, void* d_ws, size_t ws_size,
                              hipStream_t stream) {
  const float* img = (const float*)d_in[0];   // (8,1,512,512)
  const float* bw  = (const float*)d_in[1];   // (256,3,7,7)
  const float* bb  = (const float*)d_in[2];   // (256,)
  const float* fcw = (const float*)d_in[3];   // (11,256)
  const float* fcb = (const float*)d_in[4];   // (11,)
  const float* hw  = (const float*)d_in[5];   // (3,256,2)
  const float* hb  = (const float*)d_in[6];   // (3,2)
  float* out = (float*)d_out;                 // (8,11,2) f32

  float* ws     = (float*)d_ws;
  float* fold   = ws + FOLD_OFF;
  float* pval   = ws + PVAL_OFF;
  int*   pidx   = (int*)(ws + PIDX_OFF);

  fold_kernel<<<213, 256, 0, stream>>>(bw, bb, fcw, fcb, hw, hb, fold);
  score_argmax_kernel<<<BATCH*NSPLIT, 256, 0, stream>>>(img, fold, pval, pidx);
  cascade_kernel<<<NBK, 64, 0, stream>>>(img, fold, pval, pidx, out);
}